// Round 1
// baseline (371.529 us; speedup 1.0000x reference)
//
#include <hip/hip_runtime.h>

#define Bn 8
#define Cn 256
#define Hn 128
#define Wn 128
// H*W = 16384 = 1<<14; W = 1<<7

// Kernel 1: 3x3 conv (2 out channels) per pixel, fused into bilinear weight +
// base-index precompute. One thread per (b,h,w) pixel; loops 256 channels.
__global__ __launch_bounds__(256) void conv_offset_kernel(
    const float* __restrict__ x, const float* __restrict__ wconv,
    const float* __restrict__ bconv, float4* __restrict__ wts,
    int* __restrict__ basei)
{
    int gid = blockIdx.x * 256 + threadIdx.x;   // 0 .. B*H*W-1
    int w = gid & (Wn - 1);
    int h = (gid >> 7) & (Hn - 1);
    int b = gid >> 14;

    const float* xb = x + (size_t)b * Cn * Hn * Wn + h * Wn + w;

    // zero-padding masks (loop-invariant)
    const bool hm = (h > 0), hp = (h < Hn - 1);
    const bool wm = (w > 0), wp = (w < Wn - 1);

    float acc0 = bconv[0];
    float acc1 = bconv[1];

    #pragma unroll 4
    for (int c = 0; c < Cn; ++c) {
        const float* xc = xb + c * (Hn * Wn);
        float v00 = (hm && wm) ? xc[-Wn - 1] : 0.f;
        float v01 = (hm)       ? xc[-Wn]     : 0.f;
        float v02 = (hm && wp) ? xc[-Wn + 1] : 0.f;
        float v10 = (wm)       ? xc[-1]      : 0.f;
        float v11 =              xc[0];
        float v12 = (wp)       ? xc[1]       : 0.f;
        float v20 = (hp && wm) ? xc[Wn - 1]  : 0.f;
        float v21 = (hp)       ? xc[Wn]      : 0.f;
        float v22 = (hp && wp) ? xc[Wn + 1]  : 0.f;

        // w_conv layout: [2][C][3][3] — uniform addresses -> s_load expected
        const float* w0 = wconv + c * 9;
        const float* w1 = wconv + (Cn * 9) + c * 9;
        acc0 = fmaf(v00, w0[0], acc0); acc0 = fmaf(v01, w0[1], acc0);
        acc0 = fmaf(v02, w0[2], acc0); acc0 = fmaf(v10, w0[3], acc0);
        acc0 = fmaf(v11, w0[4], acc0); acc0 = fmaf(v12, w0[5], acc0);
        acc0 = fmaf(v20, w0[6], acc0); acc0 = fmaf(v21, w0[7], acc0);
        acc0 = fmaf(v22, w0[8], acc0);
        acc1 = fmaf(v00, w1[0], acc1); acc1 = fmaf(v01, w1[1], acc1);
        acc1 = fmaf(v02, w1[2], acc1); acc1 = fmaf(v10, w1[3], acc1);
        acc1 = fmaf(v11, w1[4], acc1); acc1 = fmaf(v12, w1[5], acc1);
        acc1 = fmaf(v20, w1[6], acc1); acc1 = fmaf(v21, w1[7], acc1);
        acc1 = fmaf(v22, w1[8], acc1);
    }

    // px along H (rows), py along W (cols); clip to [0, H-2]/[0, W-2]
    float px = (float)h + acc0;
    float py = (float)w + acc1;
    px = fminf(fmaxf(px, 0.f), (float)(Hn - 2));
    py = fminf(fmaxf(py, 0.f), (float)(Wn - 2));
    float fx = floorf(px), fy = floorf(py);
    float dx = px - fx, dy = py - fy;
    int qx0 = (int)fx, qy0 = (int)fy;

    // g_lt=(1-dx)(1-dy)@(qx0,qy0) g_rb=dx*dy@(qx1,qy1)
    // g_lb=(1-dx)*dy@(qx0,qy1)    g_rt=dx*(1-dy)@(qx1,qy0)
    float4 g;
    g.x = (1.f - dx) * (1.f - dy);
    g.y = dx * dy;
    g.z = (1.f - dx) * dy;
    g.w = dx * (1.f - dy);
    wts[gid] = g;
    basei[gid] = qx0 * Wn + qy0;
}

// Kernel 2: bilinear gather over channels. One thread per (b,h,w);
// weights/base live in registers, loop c with coalesced stores.
__global__ __launch_bounds__(256) void sample_kernel(
    const float* __restrict__ x, const float4* __restrict__ wts,
    const int* __restrict__ basei, float* __restrict__ out)
{
    int gid = blockIdx.x * 256 + threadIdx.x;
    int hw = gid & (Hn * Wn - 1);
    int b = gid >> 14;

    float4 g = wts[gid];
    int bs = basei[gid];

    const float* xb = x + (size_t)b * Cn * Hn * Wn + bs;
    float* ob = out + (size_t)b * Cn * Hn * Wn + hw;

    #pragma unroll 4
    for (int c = 0; c < Cn; ++c) {
        const float* xc = xb + c * (Hn * Wn);
        float lt = xc[0];
        float lb = xc[1];
        float rt = xc[Wn];
        float rb = xc[Wn + 1];
        ob[c * (Hn * Wn)] = g.x * lt + g.y * rb + g.z * lb + g.w * rt;
    }
}

extern "C" void kernel_launch(void* const* d_in, const int* in_sizes, int n_in,
                              void* d_out, int out_size, void* d_ws, size_t ws_size,
                              hipStream_t stream) {
    const float* x     = (const float*)d_in[0];
    const float* wconv = (const float*)d_in[1];
    const float* bconv = (const float*)d_in[2];
    float* out = (float*)d_out;

    const int npix = Bn * Hn * Wn;  // 131072
    float4* wts  = (float4*)d_ws;
    int*    basei = (int*)((char*)d_ws + (size_t)npix * sizeof(float4));

    conv_offset_kernel<<<npix / 256, 256, 0, stream>>>(x, wconv, bconv, wts, basei);
    sample_kernel<<<npix / 256, 256, 0, stream>>>(x, wts, basei, out);
}